// Round 12
// baseline (1479.995 us; speedup 1.0000x reference)
//
#include <hip/hip_runtime.h>
#include <hip/hip_bf16.h>

typedef float f32x4 __attribute__((ext_vector_type(4)));
typedef short s16x8 __attribute__((ext_vector_type(8)));

__device__ __forceinline__ float pv_sigm(float x){ return 1.0f/(1.0f + __expf(-x)); }
__device__ __forceinline__ float pv_tanh(float x){ float e = __expf(2.0f*x); return 1.0f - 2.0f/(e + 1.0f); }

__device__ __forceinline__ unsigned short pv_f2b(float x){
  union { float f; unsigned u; } c; c.f = x;
  unsigned r = (c.u + 0x7fffu + ((c.u >> 16) & 1u)) >> 16;
  return (unsigned short)r;
}
__device__ __forceinline__ unsigned pv_pack2(float a, float b){
  return ((unsigned)pv_f2b(b) << 16) | (unsigned)pv_f2b(a);
}
__device__ __forceinline__ float pv_lo(unsigned u){
  union { unsigned u; float f; } c; c.u = u << 16; return c.f;
}
__device__ __forceinline__ float pv_hi(unsigned u){
  union { unsigned u; float f; } c; c.u = u & 0xffff0000u; return c.f;
}

// manual OCP e4m3fn encode (RNE); valid for |x| < 448
__device__ __forceinline__ unsigned char pv_fp8(float x){
  union { float f; unsigned u; } c; c.f = x;
  unsigned s = (c.u >> 24) & 0x80u;
  unsigned au = c.u & 0x7fffffffu;
  if (au == 0u) return (unsigned char)s;
  int ex = (int)(au >> 23) - 127;
  if (ex < -6) ex = -6;
  union { unsigned u; float f; } iv; iv.u = (unsigned)(3 - ex + 127) << 23;
  union { unsigned u; float f; } a;  a.u = au;
  int q = (int)rintf(a.f * iv.f);
  if (q >= 16) { q >>= 1; ex += 1; }
  unsigned bits;
  if (ex == -6 && q < 8) bits = (unsigned)q;
  else bits = (unsigned)(((ex + 7) << 3) | (q - 8));
  return (unsigned char)(s | bits);
}

// ---------------------------------------------------------------------------
// pv_prep_gru8: pack gru weights into fp8 MFMA B-fragment order.
// 49 gate-tiles of 16 x 9 K-chunks of 32 x 64 lanes; each entry = 8 fp8.
//   n = T*16 + (l&15), k = c*32 + (l>>4)*8 + e
//   k<261        -> 8*Whh[n][k]
//   261<=k<266   -> (n<522) ? 8*Wih[n][256+k-261] : 0   (noise/time for r,z)
// ---------------------------------------------------------------------------
__global__ void pv_prep_gru8(const float* Whh, const float* Wih,
                             unsigned long long* wfp8){
  int idx = blockIdx.x*256 + threadIdx.x;   // < 49*9*64 = 28224
  if (idx >= 28224) return;
  int T = idx / 576;
  int rem = idx - T*576;
  int c = rem >> 6;
  int l = rem & 63;
  int n = T*16 + (l & 15);
  int quad = l >> 4;
  unsigned long long v = 0ull;
  #pragma unroll
  for (int e = 0; e < 8; ++e) {
    int k = c*32 + quad*8 + e;
    float w = 0.0f;
    if (n < 783) {
      if (k < 261) w = Whh[n*261 + k];
      else if (k < 266 && n < 522) w = Wih[n*261 + 256 + (k - 261)];
    }
    v |= (unsigned long long)pv_fp8(8.0f*w) << (8*e);
  }
  wfp8[idx] = v;
}

// ---------------------------------------------------------------------------
// pv_gemm: xg = leaky(pose @ projW^T + projb, 0.1) @ lstm_Wih^T + bih + bhh
// bf16 MFMA 16x16x32, 128x128 tile, BK=32. (unchanged)
// ---------------------------------------------------------------------------
__global__ __launch_bounds__(256) void pv_gemm(
    const float* pose, const float* projW, const float* projb,
    const float* Wih, const float* bih, const float* bhh,
    float* xg)
{
  __shared__ __align__(16) unsigned As[128*24];
  __shared__ __align__(16) unsigned Bs[128*24];
  __shared__ float Ws[320];

  const int tid = threadIdx.x;
  const int m0 = blockIdx.x * 128;
  const int n0 = blockIdx.y * 128;

  const int rl = tid >> 1;
  const int kh = tid & 1;
  float p0,p1,p2,p3,p4,p5,p6,p7,p8;
  {
    const float* pr = pose + (m0 + rl) * 9;
    p0=pr[0]; p1=pr[1]; p2=pr[2]; p3=pr[3]; p4=pr[4];
    p5=pr[5]; p6=pr[6]; p7=pr[7]; p8=pr[8];
  }

  const int wave = tid >> 6;
  const int lane = tid & 63;
  const int wm = wave >> 1, wn = wave & 1;
  const int l16 = lane & 15, quad = lane >> 4;

  f32x4 acc[4][4];
  #pragma unroll
  for (int i = 0; i < 4; ++i)
    #pragma unroll
    for (int j = 0; j < 4; ++j) acc[i][j] = (f32x4){0.f,0.f,0.f,0.f};

  for (int kk = 0; kk < 128; ++kk) {
    __syncthreads();
    for (int idx = tid; idx < 320; idx += 256)
      Ws[idx] = (idx < 288) ? projW[kk*288 + idx] : projb[kk*32 + (idx - 288)];
    #pragma unroll
    for (int i = 0; i < 8; ++i) {
      int q = tid + i*256;
      int nl = q >> 4;
      int kp = q & 15;
      const float* src = Wih + (n0 + nl)*4096 + kk*32 + kp*2;
      Bs[nl*24 + kp] = pv_pack2(src[0], src[1]);
    }
    __syncthreads();
    {
      const int kbase = kh*16;
      const float* wbase = Ws + kbase*9;
      float av[16];
      #pragma unroll
      for (int u = 0; u < 16; ++u) {
        const float* wr = wbase + u*9;
        float s = Ws[288 + kbase + u]
                + p0*wr[0] + p1*wr[1] + p2*wr[2] + p3*wr[3] + p4*wr[4]
                + p5*wr[5] + p6*wr[6] + p7*wr[7] + p8*wr[8];
        av[u] = fmaxf(s, 0.1f*s);
      }
      #pragma unroll
      for (int q = 0; q < 8; ++q)
        As[rl*24 + kh*8 + q] = pv_pack2(av[2*q], av[2*q+1]);
    }
    __syncthreads();
    const unsigned short* As16 = (const unsigned short*)As;
    const unsigned short* Bs16 = (const unsigned short*)Bs;
    s16x8 af[4], bfv[4];
    #pragma unroll
    for (int i = 0; i < 4; ++i)
      af[i] = *(const s16x8*)(As16 + (wm*64 + i*16 + l16)*48 + quad*8);
    #pragma unroll
    for (int j = 0; j < 4; ++j)
      bfv[j] = *(const s16x8*)(Bs16 + (wn*64 + j*16 + l16)*48 + quad*8);
    #pragma unroll
    for (int i = 0; i < 4; ++i)
      #pragma unroll
      for (int j = 0; j < 4; ++j)
        acc[i][j] = __builtin_amdgcn_mfma_f32_16x16x32_bf16(af[i], bfv[j], acc[i][j], 0, 0, 0);
  }
  #pragma unroll
  for (int j = 0; j < 4; ++j) {
    int col = n0 + wn*64 + j*16 + l16;
    float bsum = bih[col] + bhh[col];
    #pragma unroll
    for (int i = 0; i < 4; ++i) {
      #pragma unroll
      for (int r = 0; r < 4; ++r) {
        int row = m0 + wm*64 + i*16 + quad*4 + r;
        int bb = row / 100;
        int tt = row - bb*100;
        xg[(tt*128 + bb)*512 + col] = acc[i][j][r] + bsum;
      }
    }
  }
}

// ---------------------------------------------------------------------------
// pv_lstm (MFMA): 8 WGs x 1024 threads, 16 batches/WG.  Whh bf16 B-frags
// in VGPRs (32 regs); h bf16 in LDS. (unchanged from round 11)
// ---------------------------------------------------------------------------
__global__ __launch_bounds__(1024, 4) void pv_lstm(
    const float* xg, const float* Whh, float* hT)
{
  __shared__ __align__(16) unsigned short Hs[16*136];  // h bf16, row stride 136
  __shared__ float Ds[16*544];                         // gates (D + xg)
  const int tid = threadIdx.x;
  const int wv = tid >> 6;
  const int lane = tid & 63;
  const int l16 = lane & 15, quad = lane >> 4;
  const int m0 = blockIdx.x * 16;

  s16x8 bfr[2][4];
  #pragma unroll
  for (int tt = 0; tt < 2; ++tt) {
    const int g = (wv*2 + tt)*16 + l16;
    #pragma unroll
    for (int c = 0; c < 4; ++c) {
      s16x8 v;
      #pragma unroll
      for (int e = 0; e < 8; ++e)
        v[e] = (short)pv_f2b(Whh[g*128 + c*32 + quad*8 + e]);
      bfr[tt][c] = v;
    }
  }
  for (int i = tid; i < 16*136; i += 1024) Hs[i] = 0;
  float cst[2] = {0.0f, 0.0f};
  __syncthreads();

  for (int t = 0; t < 100; ++t) {
    float xv[2][4];
    #pragma unroll
    for (int tt = 0; tt < 2; ++tt) {
      const int g = (wv*2 + tt)*16 + l16;
      #pragma unroll
      for (int r = 0; r < 4; ++r)
        xv[tt][r] = xg[(t*128 + m0 + quad*4 + r)*512 + g];
    }
    f32x4 acc0 = {0,0,0,0}, acc1 = {0,0,0,0};
    #pragma unroll
    for (int c = 0; c < 4; ++c) {
      s16x8 a = *(const s16x8*)(Hs + l16*136 + c*32 + quad*8);
      acc0 = __builtin_amdgcn_mfma_f32_16x16x32_bf16(a, bfr[0][c], acc0, 0, 0, 0);
      acc1 = __builtin_amdgcn_mfma_f32_16x16x32_bf16(a, bfr[1][c], acc1, 0, 0, 0);
    }
    #pragma unroll
    for (int r = 0; r < 4; ++r) {
      Ds[(quad*4 + r)*544 + (wv*2 + 0)*16 + l16] = acc0[r] + xv[0][r];
      Ds[(quad*4 + r)*544 + (wv*2 + 1)*16 + l16] = acc1[r] + xv[1][r];
    }
    __syncthreads();
    #pragma unroll
    for (int e = 0; e < 2; ++e) {
      const int el = tid + e*1024;
      const int m = el >> 7, j = el & 127;
      float gi = Ds[m*544 + j];
      float gf = Ds[m*544 + 128 + j];
      float gg = Ds[m*544 + 256 + j];
      float go = Ds[m*544 + 384 + j];
      float c = pv_sigm(gf)*cst[e] + pv_sigm(gi)*pv_tanh(gg);
      cst[e] = c;
      float h = pv_sigm(go)*pv_tanh(c);
      Hs[m*136 + j] = pv_f2b(h);
      if (t == 99) hT[(m0 + m)*128 + j] = h;
    }
    __syncthreads();
  }
}

// ---------------------------------------------------------------------------
// pv_head: unchanged.
// ---------------------------------------------------------------------------
__global__ __launch_bounds__(64) void pv_head(
    const float* hT, const float* eps,
    const float* muW, const float* mub,
    const float* lvW, const float* lvb,
    const float* fcW, const float* fcb,
    float* xvec, float* out)
{
  __shared__ float hrow[128];
  __shared__ float emb[64];
  const int b = blockIdx.x, j = threadIdx.x;
  hrow[j] = hT[b*128 + j];
  hrow[j + 64] = hT[b*128 + 64 + j];
  __syncthreads();
  float sm = mub[j], sl = lvb[j];
  for (int k = 0; k < 128; ++k) {
    sm += hrow[k]*muW[j*128 + k];
    sl += hrow[k]*lvW[j*128 + k];
  }
  float mu = fmaxf(sm, 0.1f*sm);
  float lv = fmaxf(sl, 0.1f*sl);
  lv = fminf(fmaxf(lv, -10.0f), 10.0f);
  float em = mu + eps[b*64 + j]*__expf(0.5f*lv);
  emb[j] = em;
  out[115200 + b*64 + j] = mu;
  out[123392 + b*64 + j] = lv;
  __syncthreads();
  for (int c4 = 0; c4 < 4; ++c4) {
    int c = c4*64 + j;
    float s = fcb[c];
    for (int k = 0; k < 64; ++k) s += emb[k]*fcW[c*64 + k];
    xvec[b*256 + c] = s;
  }
}

// ---------------------------------------------------------------------------
// pv_gxbase: unchanged.
// ---------------------------------------------------------------------------
__global__ __launch_bounds__(256) void pv_gxbase(
    const float* xvec, const float* Wih,
    const float* bih, const float* bhh, float* gxb)
{
  __shared__ float xs[8*256];
  const int tid = threadIdx.x;
  const int bg = blockIdx.x;
  const int gg = blockIdx.y;
  for (int i = tid; i < 2048; i += 256) xs[i] = xvec[bg*2048 + i];
  __syncthreads();
  const int g = gg*256 + tid;
  if (g >= 783) return;
  float bias = bih[g] + ((g < 522) ? bhh[g] : 0.0f);
  float a0=bias,a1=bias,a2=bias,a3=bias,a4=bias,a5=bias,a6=bias,a7=bias;
  const float* wr = Wih + g*261;
  for (int k = 0; k < 256; ++k) {
    float w = wr[k];
    a0 += xs[0*256 + k]*w; a1 += xs[1*256 + k]*w;
    a2 += xs[2*256 + k]*w; a3 += xs[3*256 + k]*w;
    a4 += xs[4*256 + k]*w; a5 += xs[5*256 + k]*w;
    a6 += xs[6*256 + k]*w; a7 += xs[7*256 + k]*w;
  }
  gxb[(bg*8 + 0)*783 + g] = a0; gxb[(bg*8 + 1)*783 + g] = a1;
  gxb[(bg*8 + 2)*783 + g] = a2; gxb[(bg*8 + 3)*783 + g] = a3;
  gxb[(bg*8 + 4)*783 + g] = a4; gxb[(bg*8 + 5)*783 + g] = a5;
  gxb[(bg*8 + 6)*783 + g] = a6; gxb[(bg*8 + 7)*783 + g] = a7;
}

// ---------------------------------------------------------------------------
// pv_gru: 8 WGs x 1024 threads, 16 batches/WG.
// Wave wv owns tiles {3wv..3wv+2} as fp8 B-frags PINNED in VGPRs (54 regs,
// asm-pinned so the allocator cannot sink the loads back into the loop).
// Tile 48 (gates 768..782) is streamed per step by wave 15 only (4.6 KB,
// L1-resident).  launch_bounds(1024,1): flat-WG clamp gives 128-VGPR cap.
// ---------------------------------------------------------------------------
__global__ __launch_bounds__(1024, 1) void pv_gru(
    const float* gxb, const unsigned long long* wfp8, const float* Wih,
    const float* bhh, const float* noise, float* hseq)
{
  __shared__ __align__(16) unsigned char Afp8[16*296];  // A fp8, row stride 296
  __shared__ float Ds[16*788];                          // D, row stride 788
  __shared__ float WihN[261*5];                         // n-gate noise/time weights
  __shared__ float bhhN[261];

  const int tid = threadIdx.x;
  const int wv = tid >> 6;
  const int lane = tid & 63;
  const int l16 = lane & 15, quad = lane >> 4;
  const int m0 = blockIdx.x * 16;
  const int tbase = wv*3;                   // tiles 3wv..3wv+2 (0..47)

  long bfr[3][9];
  #pragma unroll
  for (int tt = 0; tt < 3; ++tt)
    #pragma unroll
    for (int c = 0; c < 9; ++c)
      bfr[tt][c] = (long)wfp8[((tbase + tt)*9 + c)*64 + lane];
  // pin the resident fragments in VGPRs — forbid load sinking/remat
  #pragma unroll
  for (int tt = 0; tt < 3; ++tt)
    #pragma unroll
    for (int c = 0; c < 9; ++c)
      asm volatile("" : "+v"(bfr[tt][c]));

  for (int i = tid; i < 261*5; i += 1024) WihN[i] = Wih[(522 + i/5)*261 + 256 + (i % 5)];
  for (int i = tid; i < 261; i += 1024) bhhN[i] = bhh[522 + i];
  for (int i = tid; i < 16*296; i += 1024) Afp8[i] = 0;
  __syncthreads();
  if (tid < 80) {   // A noise/time columns for t=0 (time_0 = 0)
    const int m = tid/5, i = tid - (tid/5)*5;
    float v = (i < 4) ? noise[(m0 + m)*4 + i]*0.1f : 0.0f;
    Afp8[m*296 + 261 + i] = pv_fp8(4.0f*v);
  }
  float hreg[5] = {0,0,0,0,0};
  __syncthreads();

  for (int t = 0; t < 100; ++t) {
    // wave 15 streams tile 48's fragments (same addresses every step -> L1)
    long b48[9];
    if (wv == 15) {
      #pragma unroll
      for (int c = 0; c < 9; ++c)
        b48[c] = (long)wfp8[(48*9 + c)*64 + lane];
    }
    f32x4 acc[3];
    f32x4 acc48 = {0,0,0,0};
    #pragma unroll
    for (int tt = 0; tt < 3; ++tt) acc[tt] = (f32x4){0,0,0,0};
    #pragma unroll
    for (int c = 0; c < 9; ++c) {
      const long a = *(const long*)(Afp8 + l16*296 + c*32 + quad*8);
      #pragma unroll
      for (int tt = 0; tt < 3; ++tt)
        acc[tt] = __builtin_amdgcn_mfma_f32_16x16x32_fp8_fp8(a, bfr[tt][c], acc[tt], 0, 0, 0);
      if (wv == 15)
        acc48 = __builtin_amdgcn_mfma_f32_16x16x32_fp8_fp8(a, b48[c], acc48, 0, 0, 0);
    }
    #pragma unroll
    for (int tt = 0; tt < 3; ++tt) {
      const int n = (tbase + tt)*16 + l16;
      #pragma unroll
      for (int r = 0; r < 4; ++r)
        Ds[(quad*4 + r)*788 + n] = acc[tt][r];
    }
    if (wv == 15) {
      const int n = 768 + l16;            // up to 783 (< 788, padded)
      #pragma unroll
      for (int r = 0; r < 4; ++r)
        Ds[(quad*4 + r)*788 + n] = acc48[r];
    }
    __syncthreads();
    const float inv32 = 1.0f/32.0f;
    const float tv = (float)t * (1.0f/99.0f);
    #pragma unroll
    for (int e = 0; e < 5; ++e) {
      const int el = tid + e*1024;
      if (el < 4176) {
        const int m = el/261, j = el - (el/261)*261;
        const float* dr = Ds + m*788;
        float Dr = dr[j]*inv32, Dz = dr[261 + j]*inv32, Dn = dr[522 + j]*inv32;
        const float* gb = gxb + (m0 + m)*783;
        const float* wn = WihN + j*5;
        const float* ne = noise + (t*128 + m0 + m)*4;
        float gn = gb[522 + j]
                 + 0.1f*(ne[0]*wn[0] + ne[1]*wn[1] + ne[2]*wn[2] + ne[3]*wn[3])
                 + tv*wn[4];
        float r_ = pv_sigm(Dr + gb[j]);
        float z_ = pv_sigm(Dz + gb[261 + j]);
        float n_ = pv_tanh(gn + r_*(Dn + bhhN[j]));
        float h = (1.0f - z_)*n_ + z_*hreg[e];
        hreg[e] = h;
        hseq[(t*128 + m0 + m)*261 + j] = h;
        Afp8[m*296 + j] = pv_fp8(4.0f*h);
      }
    }
    if (tid < 80 && t < 99) {   // A noise/time for t+1
      const int m = tid/5, i = tid - (tid/5)*5;
      float v = (i < 4) ? noise[((t+1)*128 + m0 + m)*4 + i]*0.1f
                        : (t+1)*(1.0f/99.0f);
      Afp8[m*296 + 261 + i] = pv_fp8(4.0f*v);
    }
    __syncthreads();
  }
}

// ---------------------------------------------------------------------------
// pv_frames: unchanged.
// ---------------------------------------------------------------------------
__global__ __launch_bounds__(256) void pv_frames(
    const float* hseq, const float* W1, const float* b1,
    const float* W2, const float* b2, float* out)
{
  __shared__ __align__(16) float h16[16*264];
  __shared__ unsigned w1p[64*133];
  __shared__ float f1s[16*66];
  __shared__ float w2s[576];
  const int tid = threadIdx.x;
  const int r0 = blockIdx.x * 16;    // rows rt = t*128 + b
  for (int i = tid; i < 16*264; i += 256) {
    int r = i / 264, k = i - r*264;
    h16[i] = (k < 261) ? hseq[(r0 + r)*261 + k] : 0.0f;
  }
  for (int i = tid; i < 64*131; i += 256) {
    int c = i/131, kp = i - (i/131)*131;
    int k = kp*2;
    float a0 = W1[c*261 + k];
    float a1 = (k + 1 < 261) ? W1[c*261 + k + 1] : 0.0f;
    w1p[c*133 + kp] = pv_pack2(a0, a1);
  }
  for (int i = tid; i < 576; i += 256) w2s[i] = W2[i];
  __syncthreads();
  #pragma unroll
  for (int e = 0; e < 4; ++e) {
    const int el = tid + e*256;
    const int r = el >> 6, c = el & 63;
    float s = b1[c];
    const unsigned* wp = w1p + c*133;
    const float* hr = h16 + r*264;
    for (int kp = 0; kp < 131; ++kp) {
      unsigned w = wp[kp];
      s += pv_lo(w)*hr[2*kp] + pv_hi(w)*hr[2*kp + 1];
    }
    f1s[r*66 + c] = fmaxf(s, 0.2f*s);
  }
  __syncthreads();
  if (tid < 144) {
    const int r = tid/9, oc = tid - (tid/9)*9;
    float s = b2[oc];
    const float* fr = f1s + r*66;
    const float* w = w2s + oc*64;
    #pragma unroll 8
    for (int k = 0; k < 64; ++k) s += fr[k]*w[k];
    const int rt = r0 + r;
    const int tt = rt >> 7, bb = rt & 127;
    out[bb*900 + tt*9 + oc] = pv_sigm(s);
  }
}

// ---------------------------------------------------------------------------
extern "C" __attribute__((visibility("default")))
void kernel_launch(void* const* d_in, const int* in_sizes, int n_in,
                   void* d_out, int out_size, void* d_ws, size_t ws_size,
                   hipStream_t stream)
{
  (void)in_sizes; (void)n_in; (void)out_size; (void)ws_size;
  const float* input_data = (const float*)d_in[0];
  const float* eps        = (const float*)d_in[1];
  const float* noise_eps  = (const float*)d_in[2];
  const float* proj_W     = (const float*)d_in[3];
  const float* proj_b     = (const float*)d_in[4];
  const float* lstm_Wih   = (const float*)d_in[5];
  const float* lstm_Whh   = (const float*)d_in[6];
  const float* lstm_bih   = (const float*)d_in[7];
  const float* lstm_bhh   = (const float*)d_in[8];
  const float* mu_W       = (const float*)d_in[9];
  const float* mu_b       = (const float*)d_in[10];
  const float* lv_W       = (const float*)d_in[11];
  const float* lv_b       = (const float*)d_in[12];
  const float* fcin_W     = (const float*)d_in[13];
  const float* fcin_b     = (const float*)d_in[14];
  const float* gru_Wih    = (const float*)d_in[15];
  const float* gru_Whh    = (const float*)d_in[16];
  const float* gru_bih    = (const float*)d_in[17];
  const float* gru_bhh    = (const float*)d_in[18];
  const float* jf_W1      = (const float*)d_in[19];
  const float* jf_b1      = (const float*)d_in[20];
  const float* jf_W2      = (const float*)d_in[21];
  const float* jf_b2      = (const float*)d_in[22];

  char* w = (char*)d_ws;
  float*              xg   = (float*)(w);                          // 26,214,400 B
  unsigned long long* wfp8 = (unsigned long long*)(w + 26214400);  //    225,792 B
  float*              hT   = (float*)(w + 26440192);               //     65,536 B
  float*              xvec = (float*)(w + 26505728);               //    131,072 B
  float*              gxb  = (float*)(w + 26636800);               //    400,896 B
  float*              hseq = (float*)(w + 27037696);               // 13,363,200 B (end 40.4 MB)
  float*              outf = (float*)d_out;

  pv_prep_gru8<<<111, 256, 0, stream>>>(gru_Whh, gru_Wih, wfp8);
  pv_gemm<<<dim3(100, 4), 256, 0, stream>>>(input_data, proj_W, proj_b,
                                            lstm_Wih, lstm_bih, lstm_bhh, xg);
  pv_lstm<<<8, 1024, 0, stream>>>(xg, lstm_Whh, hT);
  pv_head<<<128, 64, 0, stream>>>(hT, eps, mu_W, mu_b, lv_W, lv_b,
                                  fcin_W, fcin_b, xvec, outf);
  pv_gxbase<<<dim3(16, 4), 256, 0, stream>>>(xvec, gru_Wih, gru_bih, gru_bhh, gxb);
  pv_gru<<<8, 1024, 0, stream>>>(gxb, wfp8, gru_Wih, gru_bhh, noise_eps, hseq);
  pv_frames<<<800, 256, 0, stream>>>(hseq, jf_W1, jf_b1, jf_W2, jf_b2, outf);
}

// Round 13
// 1332.344 us; speedup vs baseline: 1.1108x; 1.1108x over previous
//
#include <hip/hip_runtime.h>
#include <hip/hip_bf16.h>

typedef float f32x4 __attribute__((ext_vector_type(4)));
typedef short s16x8 __attribute__((ext_vector_type(8)));

__device__ __forceinline__ float pv_sigm(float x){ return 1.0f/(1.0f + __expf(-x)); }
__device__ __forceinline__ float pv_tanh(float x){ float e = __expf(2.0f*x); return 1.0f - 2.0f/(e + 1.0f); }

__device__ __forceinline__ unsigned short pv_f2b(float x){
  union { float f; unsigned u; } c; c.f = x;
  unsigned r = (c.u + 0x7fffu + ((c.u >> 16) & 1u)) >> 16;
  return (unsigned short)r;
}
__device__ __forceinline__ unsigned pv_pack2(float a, float b){
  return ((unsigned)pv_f2b(b) << 16) | (unsigned)pv_f2b(a);
}
__device__ __forceinline__ float pv_lo(unsigned u){
  union { unsigned u; float f; } c; c.u = u << 16; return c.f;
}
__device__ __forceinline__ float pv_hi(unsigned u){
  union { unsigned u; float f; } c; c.u = u & 0xffff0000u; return c.f;
}

// manual OCP e4m3fn encode (RNE); valid for |x| < 448
__device__ __forceinline__ unsigned char pv_fp8(float x){
  union { float f; unsigned u; } c; c.f = x;
  unsigned s = (c.u >> 24) & 0x80u;
  unsigned au = c.u & 0x7fffffffu;
  if (au == 0u) return (unsigned char)s;
  int ex = (int)(au >> 23) - 127;
  if (ex < -6) ex = -6;
  union { unsigned u; float f; } iv; iv.u = (unsigned)(3 - ex + 127) << 23;
  union { unsigned u; float f; } a;  a.u = au;
  int q = (int)rintf(a.f * iv.f);
  if (q >= 16) { q >>= 1; ex += 1; }
  unsigned bits;
  if (ex == -6 && q < 8) bits = (unsigned)q;
  else bits = (unsigned)(((ex + 7) << 3) | (q - 8));
  return (unsigned char)(s | bits);
}

// ---------------------------------------------------------------------------
// pv_prep_gru8: pack gru weights into fp8 MFMA B-fragment order.
// 49 gate-tiles of 16 x 9 K-chunks of 32 x 64 lanes; each entry = 8 fp8.
//   n = T*16 + (l&15), k = c*32 + (l>>4)*8 + e
//   k<261        -> 8*Whh[n][k]
//   261<=k<266   -> (n<522) ? 8*Wih[n][256+k-261] : 0   (noise/time for r,z)
// ---------------------------------------------------------------------------
__global__ void pv_prep_gru8(const float* Whh, const float* Wih,
                             unsigned long long* wfp8){
  int idx = blockIdx.x*256 + threadIdx.x;   // < 49*9*64 = 28224
  if (idx >= 28224) return;
  int T = idx / 576;
  int rem = idx - T*576;
  int c = rem >> 6;
  int l = rem & 63;
  int n = T*16 + (l & 15);
  int quad = l >> 4;
  unsigned long long v = 0ull;
  #pragma unroll
  for (int e = 0; e < 8; ++e) {
    int k = c*32 + quad*8 + e;
    float w = 0.0f;
    if (n < 783) {
      if (k < 261) w = Whh[n*261 + k];
      else if (k < 266 && n < 522) w = Wih[n*261 + 256 + (k - 261)];
    }
    v |= (unsigned long long)pv_fp8(8.0f*w) << (8*e);
  }
  wfp8[idx] = v;
}

// ---------------------------------------------------------------------------
// pv_gemm: xg = leaky(pose @ projW^T + projb, 0.1) @ lstm_Wih^T + bih + bhh
// bf16 MFMA 16x16x32, 128x128 tile, BK=32. (unchanged)
// ---------------------------------------------------------------------------
__global__ __launch_bounds__(256) void pv_gemm(
    const float* pose, const float* projW, const float* projb,
    const float* Wih, const float* bih, const float* bhh,
    float* xg)
{
  __shared__ __align__(16) unsigned As[128*24];
  __shared__ __align__(16) unsigned Bs[128*24];
  __shared__ float Ws[320];

  const int tid = threadIdx.x;
  const int m0 = blockIdx.x * 128;
  const int n0 = blockIdx.y * 128;

  const int rl = tid >> 1;
  const int kh = tid & 1;
  float p0,p1,p2,p3,p4,p5,p6,p7,p8;
  {
    const float* pr = pose + (m0 + rl) * 9;
    p0=pr[0]; p1=pr[1]; p2=pr[2]; p3=pr[3]; p4=pr[4];
    p5=pr[5]; p6=pr[6]; p7=pr[7]; p8=pr[8];
  }

  const int wave = tid >> 6;
  const int lane = tid & 63;
  const int wm = wave >> 1, wn = wave & 1;
  const int l16 = lane & 15, quad = lane >> 4;

  f32x4 acc[4][4];
  #pragma unroll
  for (int i = 0; i < 4; ++i)
    #pragma unroll
    for (int j = 0; j < 4; ++j) acc[i][j] = (f32x4){0.f,0.f,0.f,0.f};

  for (int kk = 0; kk < 128; ++kk) {
    __syncthreads();
    for (int idx = tid; idx < 320; idx += 256)
      Ws[idx] = (idx < 288) ? projW[kk*288 + idx] : projb[kk*32 + (idx - 288)];
    #pragma unroll
    for (int i = 0; i < 8; ++i) {
      int q = tid + i*256;
      int nl = q >> 4;
      int kp = q & 15;
      const float* src = Wih + (n0 + nl)*4096 + kk*32 + kp*2;
      Bs[nl*24 + kp] = pv_pack2(src[0], src[1]);
    }
    __syncthreads();
    {
      const int kbase = kh*16;
      const float* wbase = Ws + kbase*9;
      float av[16];
      #pragma unroll
      for (int u = 0; u < 16; ++u) {
        const float* wr = wbase + u*9;
        float s = Ws[288 + kbase + u]
                + p0*wr[0] + p1*wr[1] + p2*wr[2] + p3*wr[3] + p4*wr[4]
                + p5*wr[5] + p6*wr[6] + p7*wr[7] + p8*wr[8];
        av[u] = fmaxf(s, 0.1f*s);
      }
      #pragma unroll
      for (int q = 0; q < 8; ++q)
        As[rl*24 + kh*8 + q] = pv_pack2(av[2*q], av[2*q+1]);
    }
    __syncthreads();
    const unsigned short* As16 = (const unsigned short*)As;
    const unsigned short* Bs16 = (const unsigned short*)Bs;
    s16x8 af[4], bfv[4];
    #pragma unroll
    for (int i = 0; i < 4; ++i)
      af[i] = *(const s16x8*)(As16 + (wm*64 + i*16 + l16)*48 + quad*8);
    #pragma unroll
    for (int j = 0; j < 4; ++j)
      bfv[j] = *(const s16x8*)(Bs16 + (wn*64 + j*16 + l16)*48 + quad*8);
    #pragma unroll
    for (int i = 0; i < 4; ++i)
      #pragma unroll
      for (int j = 0; j < 4; ++j)
        acc[i][j] = __builtin_amdgcn_mfma_f32_16x16x32_bf16(af[i], bfv[j], acc[i][j], 0, 0, 0);
  }
  #pragma unroll
  for (int j = 0; j < 4; ++j) {
    int col = n0 + wn*64 + j*16 + l16;
    float bsum = bih[col] + bhh[col];
    #pragma unroll
    for (int i = 0; i < 4; ++i) {
      #pragma unroll
      for (int r = 0; r < 4; ++r) {
        int row = m0 + wm*64 + i*16 + quad*4 + r;
        int bb = row / 100;
        int tt = row - bb*100;
        xg[(tt*128 + bb)*512 + col] = acc[i][j][r] + bsum;
      }
    }
  }
}

// ---------------------------------------------------------------------------
// pv_lstm (MFMA): 8 WGs x 1024 threads, 16 batches/WG.  Whh bf16 B-frags
// in VGPRs (32 regs, pinned); amdgpu_waves_per_eu(4,4) caps occupancy target
// at 4 waves/EU -> 128-VGPR budget, so fragments stay resident.
// ---------------------------------------------------------------------------
__global__ __attribute__((amdgpu_waves_per_eu(4, 4)))
__launch_bounds__(1024) void pv_lstm(
    const float* xg, const float* Whh, float* hT)
{
  __shared__ __align__(16) unsigned short Hs[16*136];  // h bf16, row stride 136
  __shared__ float Ds[16*544];                         // gates (D + xg)
  const int tid = threadIdx.x;
  const int wv = tid >> 6;
  const int lane = tid & 63;
  const int l16 = lane & 15, quad = lane >> 4;
  const int m0 = blockIdx.x * 16;

  s16x8 bfr[2][4];
  #pragma unroll
  for (int tt = 0; tt < 2; ++tt) {
    const int g = (wv*2 + tt)*16 + l16;
    #pragma unroll
    for (int c = 0; c < 4; ++c) {
      s16x8 v;
      #pragma unroll
      for (int e = 0; e < 8; ++e)
        v[e] = (short)pv_f2b(Whh[g*128 + c*32 + quad*8 + e]);
      bfr[tt][c] = v;
    }
  }
  #pragma unroll
  for (int tt = 0; tt < 2; ++tt)
    #pragma unroll
    for (int c = 0; c < 4; ++c)
      asm volatile("" : "+v"(bfr[tt][c]));
  for (int i = tid; i < 16*136; i += 1024) Hs[i] = 0;
  float cst[2] = {0.0f, 0.0f};
  __syncthreads();

  for (int t = 0; t < 100; ++t) {
    float xv[2][4];
    #pragma unroll
    for (int tt = 0; tt < 2; ++tt) {
      const int g = (wv*2 + tt)*16 + l16;
      #pragma unroll
      for (int r = 0; r < 4; ++r)
        xv[tt][r] = xg[(t*128 + m0 + quad*4 + r)*512 + g];
    }
    f32x4 acc0 = {0,0,0,0}, acc1 = {0,0,0,0};
    #pragma unroll
    for (int c = 0; c < 4; ++c) {
      s16x8 a = *(const s16x8*)(Hs + l16*136 + c*32 + quad*8);
      acc0 = __builtin_amdgcn_mfma_f32_16x16x32_bf16(a, bfr[0][c], acc0, 0, 0, 0);
      acc1 = __builtin_amdgcn_mfma_f32_16x16x32_bf16(a, bfr[1][c], acc1, 0, 0, 0);
    }
    #pragma unroll
    for (int r = 0; r < 4; ++r) {
      Ds[(quad*4 + r)*544 + (wv*2 + 0)*16 + l16] = acc0[r] + xv[0][r];
      Ds[(quad*4 + r)*544 + (wv*2 + 1)*16 + l16] = acc1[r] + xv[1][r];
    }
    __syncthreads();
    #pragma unroll
    for (int e = 0; e < 2; ++e) {
      const int el = tid + e*1024;
      const int m = el >> 7, j = el & 127;
      float gi = Ds[m*544 + j];
      float gf = Ds[m*544 + 128 + j];
      float gg = Ds[m*544 + 256 + j];
      float go = Ds[m*544 + 384 + j];
      float c = pv_sigm(gf)*cst[e] + pv_sigm(gi)*pv_tanh(gg);
      cst[e] = c;
      float h = pv_sigm(go)*pv_tanh(c);
      Hs[m*136 + j] = pv_f2b(h);
      if (t == 99) hT[(m0 + m)*128 + j] = h;
    }
    __syncthreads();
  }
}

// ---------------------------------------------------------------------------
// pv_head: unchanged.
// ---------------------------------------------------------------------------
__global__ __launch_bounds__(64) void pv_head(
    const float* hT, const float* eps,
    const float* muW, const float* mub,
    const float* lvW, const float* lvb,
    const float* fcW, const float* fcb,
    float* xvec, float* out)
{
  __shared__ float hrow[128];
  __shared__ float emb[64];
  const int b = blockIdx.x, j = threadIdx.x;
  hrow[j] = hT[b*128 + j];
  hrow[j + 64] = hT[b*128 + 64 + j];
  __syncthreads();
  float sm = mub[j], sl = lvb[j];
  for (int k = 0; k < 128; ++k) {
    sm += hrow[k]*muW[j*128 + k];
    sl += hrow[k]*lvW[j*128 + k];
  }
  float mu = fmaxf(sm, 0.1f*sm);
  float lv = fmaxf(sl, 0.1f*sl);
  lv = fminf(fmaxf(lv, -10.0f), 10.0f);
  float em = mu + eps[b*64 + j]*__expf(0.5f*lv);
  emb[j] = em;
  out[115200 + b*64 + j] = mu;
  out[123392 + b*64 + j] = lv;
  __syncthreads();
  for (int c4 = 0; c4 < 4; ++c4) {
    int c = c4*64 + j;
    float s = fcb[c];
    for (int k = 0; k < 64; ++k) s += emb[k]*fcW[c*64 + k];
    xvec[b*256 + c] = s;
  }
}

// ---------------------------------------------------------------------------
// pv_gxbase: unchanged.
// ---------------------------------------------------------------------------
__global__ __launch_bounds__(256) void pv_gxbase(
    const float* xvec, const float* Wih,
    const float* bih, const float* bhh, float* gxb)
{
  __shared__ float xs[8*256];
  const int tid = threadIdx.x;
  const int bg = blockIdx.x;
  const int gg = blockIdx.y;
  for (int i = tid; i < 2048; i += 256) xs[i] = xvec[bg*2048 + i];
  __syncthreads();
  const int g = gg*256 + tid;
  if (g >= 783) return;
  float bias = bih[g] + ((g < 522) ? bhh[g] : 0.0f);
  float a0=bias,a1=bias,a2=bias,a3=bias,a4=bias,a5=bias,a6=bias,a7=bias;
  const float* wr = Wih + g*261;
  for (int k = 0; k < 256; ++k) {
    float w = wr[k];
    a0 += xs[0*256 + k]*w; a1 += xs[1*256 + k]*w;
    a2 += xs[2*256 + k]*w; a3 += xs[3*256 + k]*w;
    a4 += xs[4*256 + k]*w; a5 += xs[5*256 + k]*w;
    a6 += xs[6*256 + k]*w; a7 += xs[7*256 + k]*w;
  }
  gxb[(bg*8 + 0)*783 + g] = a0; gxb[(bg*8 + 1)*783 + g] = a1;
  gxb[(bg*8 + 2)*783 + g] = a2; gxb[(bg*8 + 3)*783 + g] = a3;
  gxb[(bg*8 + 4)*783 + g] = a4; gxb[(bg*8 + 5)*783 + g] = a5;
  gxb[(bg*8 + 6)*783 + g] = a6; gxb[(bg*8 + 7)*783 + g] = a7;
}

// ---------------------------------------------------------------------------
// pv_gru: 8 WGs x 1024 threads, 16 batches/WG.  Whh as fp8 e4m3 MFMA
// B-frags RESIDENT IN VGPRS (x8 scale): wave wv owns tiles {3wv..} (3 or 4).
// amdgpu_waves_per_eu(4,4) -> allocator budget 128 VGPRs so the 72 pinned
// weight regs stay resident (round 12's 64-reg target forced scratch spill).
// h/noise/time in A (x4 scale); D /= 32.  Writes hseq fp32 [t][b][261].
// ---------------------------------------------------------------------------
__global__ __attribute__((amdgpu_waves_per_eu(4, 4)))
__launch_bounds__(1024) void pv_gru(
    const float* gxb, const unsigned long long* wfp8, const float* Wih,
    const float* bhh, const float* noise, float* hseq)
{
  __shared__ __align__(16) unsigned char Afp8[16*296];  // A fp8, row stride 296
  __shared__ float Ds[16*788];                          // D, row stride 788
  __shared__ float WihN[261*5];                         // n-gate noise/time weights
  __shared__ float bhhN[261];

  const int tid = threadIdx.x;
  const int wv = tid >> 6;
  const int lane = tid & 63;
  const int l16 = lane & 15, quad = lane >> 4;
  const int m0 = blockIdx.x * 16;
  const int tbase = (wv < 15) ? wv*3 : 45;
  const int ntiles = (wv < 15) ? 3 : 4;     // 49 tiles of 16 over 784 gates

  long bfr[4][9];
  #pragma unroll
  for (int tt = 0; tt < 4; ++tt) {
    if (tt < ntiles) {
      #pragma unroll
      for (int c = 0; c < 9; ++c)
        bfr[tt][c] = (long)wfp8[((tbase + tt)*9 + c)*64 + lane];
    } else {
      #pragma unroll
      for (int c = 0; c < 9; ++c) bfr[tt][c] = 0;
    }
  }
  // pin resident fragments — forbid load sinking/remat
  #pragma unroll
  for (int tt = 0; tt < 4; ++tt)
    #pragma unroll
    for (int c = 0; c < 9; ++c)
      asm volatile("" : "+v"(bfr[tt][c]));

  for (int i = tid; i < 261*5; i += 1024) WihN[i] = Wih[(522 + i/5)*261 + 256 + (i % 5)];
  for (int i = tid; i < 261; i += 1024) bhhN[i] = bhh[522 + i];
  for (int i = tid; i < 16*296; i += 1024) Afp8[i] = 0;
  __syncthreads();
  if (tid < 80) {   // A noise/time columns for t=0 (time_0 = 0)
    const int m = tid/5, i = tid - (tid/5)*5;
    float v = (i < 4) ? noise[(m0 + m)*4 + i]*0.1f : 0.0f;
    Afp8[m*296 + 261 + i] = pv_fp8(4.0f*v);
  }
  float hreg[5] = {0,0,0,0,0};
  __syncthreads();

  for (int t = 0; t < 100; ++t) {
    f32x4 acc[4];
    #pragma unroll
    for (int tt = 0; tt < 4; ++tt) acc[tt] = (f32x4){0,0,0,0};
    #pragma unroll
    for (int c = 0; c < 9; ++c) {
      const long a = *(const long*)(Afp8 + l16*296 + c*32 + quad*8);
      #pragma unroll
      for (int tt = 0; tt < 4; ++tt)
        if (tt < ntiles)
          acc[tt] = __builtin_amdgcn_mfma_f32_16x16x32_fp8_fp8(a, bfr[tt][c], acc[tt], 0, 0, 0);
    }
    #pragma unroll
    for (int tt = 0; tt < 4; ++tt)
      if (tt < ntiles) {
        const int n = (tbase + tt)*16 + l16;
        #pragma unroll
        for (int r = 0; r < 4; ++r)
          Ds[(quad*4 + r)*788 + n] = acc[tt][r];
      }
    __syncthreads();
    const float inv32 = 1.0f/32.0f;
    const float tv = (float)t * (1.0f/99.0f);
    #pragma unroll
    for (int e = 0; e < 5; ++e) {
      const int el = tid + e*1024;
      if (el < 4176) {
        const int m = el/261, j = el - (el/261)*261;
        const float* dr = Ds + m*788;
        float Dr = dr[j]*inv32, Dz = dr[261 + j]*inv32, Dn = dr[522 + j]*inv32;
        const float* gb = gxb + (m0 + m)*783;
        const float* wn = WihN + j*5;
        const float* ne = noise + (t*128 + m0 + m)*4;
        float gn = gb[522 + j]
                 + 0.1f*(ne[0]*wn[0] + ne[1]*wn[1] + ne[2]*wn[2] + ne[3]*wn[3])
                 + tv*wn[4];
        float r_ = pv_sigm(Dr + gb[j]);
        float z_ = pv_sigm(Dz + gb[261 + j]);
        float n_ = pv_tanh(gn + r_*(Dn + bhhN[j]));
        float h = (1.0f - z_)*n_ + z_*hreg[e];
        hreg[e] = h;
        hseq[(t*128 + m0 + m)*261 + j] = h;
        Afp8[m*296 + j] = pv_fp8(4.0f*h);
      }
    }
    if (tid < 80 && t < 99) {   // A noise/time for t+1
      const int m = tid/5, i = tid - (tid/5)*5;
      float v = (i < 4) ? noise[((t+1)*128 + m0 + m)*4 + i]*0.1f
                        : (t+1)*(1.0f/99.0f);
      Afp8[m*296 + 261 + i] = pv_fp8(4.0f*v);
    }
    __syncthreads();
  }
}

// ---------------------------------------------------------------------------
// pv_frames: unchanged.
// ---------------------------------------------------------------------------
__global__ __launch_bounds__(256) void pv_frames(
    const float* hseq, const float* W1, const float* b1,
    const float* W2, const float* b2, float* out)
{
  __shared__ __align__(16) float h16[16*264];
  __shared__ unsigned w1p[64*133];
  __shared__ float f1s[16*66];
  __shared__ float w2s[576];
  const int tid = threadIdx.x;
  const int r0 = blockIdx.x * 16;    // rows rt = t*128 + b
  for (int i = tid; i < 16*264; i += 256) {
    int r = i / 264, k = i - r*264;
    h16[i] = (k < 261) ? hseq[(r0 + r)*261 + k] : 0.0f;
  }
  for (int i = tid; i < 64*131; i += 256) {
    int c = i/131, kp = i - (i/131)*131;
    int k = kp*2;
    float a0 = W1[c*261 + k];
    float a1 = (k + 1 < 261) ? W1[c*261 + k + 1] : 0.0f;
    w1p[c*133 + kp] = pv_pack2(a0, a1);
  }
  for (int i = tid; i < 576; i += 256) w2s[i] = W2[i];
  __syncthreads();
  #pragma unroll
  for (int e = 0; e < 4; ++e) {
    const int el = tid + e*256;
    const int r = el >> 6, c = el & 63;
    float s = b1[c];
    const unsigned* wp = w1p + c*133;
    const float* hr = h16 + r*264;
    for (int kp = 0; kp < 131; ++kp) {
      unsigned w = wp[kp];
      s += pv_lo(w)*hr[2*kp] + pv_hi(w)*hr[2*kp + 1];
    }
    f1s[r*66 + c] = fmaxf(s, 0.2f*s);
  }
  __syncthreads();
  if (tid < 144) {
    const int r = tid/9, oc = tid - (tid/9)*9;
    float s = b2[oc];
    const float* fr = f1s + r*66;
    const float* w = w2s + oc*64;
    #pragma unroll 8
    for (int k = 0; k < 64; ++k) s += fr[k]*w[k];
    const int rt = r0 + r;
    const int tt = rt >> 7, bb = rt & 127;
    out[bb*900 + tt*9 + oc] = pv_sigm(s);
  }
}

// ---------------------------------------------------------------------------
extern "C" __attribute__((visibility("default")))
void kernel_launch(void* const* d_in, const int* in_sizes, int n_in,
                   void* d_out, int out_size, void* d_ws, size_t ws_size,
                   hipStream_t stream)
{
  (void)in_sizes; (void)n_in; (void)out_size; (void)ws_size;
  const float* input_data = (const float*)d_in[0];
  const float* eps        = (const float*)d_in[1];
  const float* noise_eps  = (const float*)d_in[2];
  const float* proj_W     = (const float*)d_in[3];
  const float* proj_b     = (const float*)d_in[4];
  const float* lstm_Wih   = (const float*)d_in[5];
  const float* lstm_Whh   = (const float*)d_in[6];
  const float* lstm_bih   = (const float*)d_in[7];
  const float* lstm_bhh   = (const float*)d_in[8];
  const float* mu_W       = (const float*)d_in[9];
  const float* mu_b       = (const float*)d_in[10];
  const float* lv_W       = (const float*)d_in[11];
  const float* lv_b       = (const float*)d_in[12];
  const float* fcin_W     = (const float*)d_in[13];
  const float* fcin_b     = (const float*)d_in[14];
  const float* gru_Wih    = (const float*)d_in[15];
  const float* gru_Whh    = (const float*)d_in[16];
  const float* gru_bih    = (const float*)d_in[17];
  const float* gru_bhh    = (const float*)d_in[18];
  const float* jf_W1      = (const float*)d_in[19];
  const float* jf_b1      = (const float*)d_in[20];
  const float* jf_W2      = (const float*)d_in[21];
  const float* jf_b2      = (const float*)d_in[22];

  char* w = (char*)d_ws;
  float*              xg   = (float*)(w);                          // 26,214,400 B
  unsigned long long* wfp8 = (unsigned long long*)(w + 26214400);  //    225,792 B
  float*              hT   = (float*)(w + 26440192);               //     65,536 B
  float*              xvec = (float*)(w + 26505728);               //    131,072 B
  float*              gxb  = (float*)(w + 26636800);               //    400,896 B
  float*              hseq = (float*)(w + 27037696);               // 13,363,200 B (end 40.4 MB)
  float*              outf = (float*)d_out;

  pv_prep_gru8<<<111, 256, 0, stream>>>(gru_Whh, gru_Wih, wfp8);
  pv_gemm<<<dim3(100, 4), 256, 0, stream>>>(input_data, proj_W, proj_b,
                                            lstm_Wih, lstm_bih, lstm_bhh, xg);
  pv_lstm<<<8, 1024, 0, stream>>>(xg, lstm_Whh, hT);
  pv_head<<<128, 64, 0, stream>>>(hT, eps, mu_W, mu_b, lv_W, lv_b,
                                  fcin_W, fcin_b, xvec, outf);
  pv_gxbase<<<dim3(16, 4), 256, 0, stream>>>(xvec, gru_Wih, gru_bih, gru_bhh, gxb);
  pv_gru<<<8, 1024, 0, stream>>>(gxb, wfp8, gru_Wih, gru_bhh, noise_eps, hseq);
  pv_frames<<<800, 256, 0, stream>>>(hseq, jf_W1, jf_b1, jf_W2, jf_b2, outf);
}

// Round 14
// 1009.934 us; speedup vs baseline: 1.4654x; 1.3192x over previous
//
#include <hip/hip_runtime.h>
#include <hip/hip_bf16.h>

typedef float f32x4 __attribute__((ext_vector_type(4)));
typedef short s16x8 __attribute__((ext_vector_type(8)));

__device__ __forceinline__ float pv_sigm(float x){ return 1.0f/(1.0f + __expf(-x)); }
__device__ __forceinline__ float pv_tanh(float x){ float e = __expf(2.0f*x); return 1.0f - 2.0f/(e + 1.0f); }

__device__ __forceinline__ unsigned short pv_f2b(float x){
  union { float f; unsigned u; } c; c.f = x;
  unsigned r = (c.u + 0x7fffu + ((c.u >> 16) & 1u)) >> 16;
  return (unsigned short)r;
}
__device__ __forceinline__ unsigned pv_pack2(float a, float b){
  return ((unsigned)pv_f2b(b) << 16) | (unsigned)pv_f2b(a);
}
__device__ __forceinline__ float pv_lo(unsigned u){
  union { unsigned u; float f; } c; c.u = u << 16; return c.f;
}
__device__ __forceinline__ float pv_hi(unsigned u){
  union { unsigned u; float f; } c; c.u = u & 0xffff0000u; return c.f;
}

// manual OCP e4m3fn encode (RNE); valid for |x| < 448
__device__ __forceinline__ unsigned char pv_fp8(float x){
  union { float f; unsigned u; } c; c.f = x;
  unsigned s = (c.u >> 24) & 0x80u;
  unsigned au = c.u & 0x7fffffffu;
  if (au == 0u) return (unsigned char)s;
  int ex = (int)(au >> 23) - 127;
  if (ex < -6) ex = -6;
  union { unsigned u; float f; } iv; iv.u = (unsigned)(3 - ex + 127) << 23;
  union { unsigned u; float f; } a;  a.u = au;
  int q = (int)rintf(a.f * iv.f);
  if (q >= 16) { q >>= 1; ex += 1; }
  unsigned bits;
  if (ex == -6 && q < 8) bits = (unsigned)q;
  else bits = (unsigned)(((ex + 7) << 3) | (q - 8));
  return (unsigned char)(s | bits);
}

#if defined(__has_builtin)
#if __has_builtin(__builtin_amdgcn_cvt_pk_fp8_f32)
#define PV_HW_FP8 1
#endif
#endif
__device__ __forceinline__ unsigned char pv_fp8_fast(float x){
#ifdef PV_HW_FP8
  return (unsigned char)__builtin_amdgcn_cvt_pk_fp8_f32(x, x, 0, false);
#else
  return pv_fp8(x);
#endif
}

// ---------------------------------------------------------------------------
// pv_prep_gru8: pack gru weights into fp8 MFMA B-fragment order. (unchanged)
// ---------------------------------------------------------------------------
__global__ void pv_prep_gru8(const float* Whh, const float* Wih,
                             unsigned long long* wfp8){
  int idx = blockIdx.x*256 + threadIdx.x;   // < 49*9*64 = 28224
  if (idx >= 28224) return;
  int T = idx / 576;
  int rem = idx - T*576;
  int c = rem >> 6;
  int l = rem & 63;
  int n = T*16 + (l & 15);
  int quad = l >> 4;
  unsigned long long v = 0ull;
  #pragma unroll
  for (int e = 0; e < 8; ++e) {
    int k = c*32 + quad*8 + e;
    float w = 0.0f;
    if (n < 783) {
      if (k < 261) w = Whh[n*261 + k];
      else if (k < 266 && n < 522) w = Wih[n*261 + 256 + (k - 261)];
    }
    v |= (unsigned long long)pv_fp8(8.0f*w) << (8*e);
  }
  wfp8[idx] = v;
}

// ---------------------------------------------------------------------------
// pv_gemm: unchanged (bf16 MFMA, 128x128 tile).
// ---------------------------------------------------------------------------
__global__ __launch_bounds__(256) void pv_gemm(
    const float* pose, const float* projW, const float* projb,
    const float* Wih, const float* bih, const float* bhh,
    float* xg)
{
  __shared__ __align__(16) unsigned As[128*24];
  __shared__ __align__(16) unsigned Bs[128*24];
  __shared__ float Ws[320];

  const int tid = threadIdx.x;
  const int m0 = blockIdx.x * 128;
  const int n0 = blockIdx.y * 128;

  const int rl = tid >> 1;
  const int kh = tid & 1;
  float p0,p1,p2,p3,p4,p5,p6,p7,p8;
  {
    const float* pr = pose + (m0 + rl) * 9;
    p0=pr[0]; p1=pr[1]; p2=pr[2]; p3=pr[3]; p4=pr[4];
    p5=pr[5]; p6=pr[6]; p7=pr[7]; p8=pr[8];
  }

  const int wave = tid >> 6;
  const int lane = tid & 63;
  const int wm = wave >> 1, wn = wave & 1;
  const int l16 = lane & 15, quad = lane >> 4;

  f32x4 acc[4][4];
  #pragma unroll
  for (int i = 0; i < 4; ++i)
    #pragma unroll
    for (int j = 0; j < 4; ++j) acc[i][j] = (f32x4){0.f,0.f,0.f,0.f};

  for (int kk = 0; kk < 128; ++kk) {
    __syncthreads();
    for (int idx = tid; idx < 320; idx += 256)
      Ws[idx] = (idx < 288) ? projW[kk*288 + idx] : projb[kk*32 + (idx - 288)];
    #pragma unroll
    for (int i = 0; i < 8; ++i) {
      int q = tid + i*256;
      int nl = q >> 4;
      int kp = q & 15;
      const float* src = Wih + (n0 + nl)*4096 + kk*32 + kp*2;
      Bs[nl*24 + kp] = pv_pack2(src[0], src[1]);
    }
    __syncthreads();
    {
      const int kbase = kh*16;
      const float* wbase = Ws + kbase*9;
      float av[16];
      #pragma unroll
      for (int u = 0; u < 16; ++u) {
        const float* wr = wbase + u*9;
        float s = Ws[288 + kbase + u]
                + p0*wr[0] + p1*wr[1] + p2*wr[2] + p3*wr[3] + p4*wr[4]
                + p5*wr[5] + p6*wr[6] + p7*wr[7] + p8*wr[8];
        av[u] = fmaxf(s, 0.1f*s);
      }
      #pragma unroll
      for (int q = 0; q < 8; ++q)
        As[rl*24 + kh*8 + q] = pv_pack2(av[2*q], av[2*q+1]);
    }
    __syncthreads();
    const unsigned short* As16 = (const unsigned short*)As;
    const unsigned short* Bs16 = (const unsigned short*)Bs;
    s16x8 af[4], bfv[4];
    #pragma unroll
    for (int i = 0; i < 4; ++i)
      af[i] = *(const s16x8*)(As16 + (wm*64 + i*16 + l16)*48 + quad*8);
    #pragma unroll
    for (int j = 0; j < 4; ++j)
      bfv[j] = *(const s16x8*)(Bs16 + (wn*64 + j*16 + l16)*48 + quad*8);
    #pragma unroll
    for (int i = 0; i < 4; ++i)
      #pragma unroll
      for (int j = 0; j < 4; ++j)
        acc[i][j] = __builtin_amdgcn_mfma_f32_16x16x32_bf16(af[i], bfv[j], acc[i][j], 0, 0, 0);
  }
  #pragma unroll
  for (int j = 0; j < 4; ++j) {
    int col = n0 + wn*64 + j*16 + l16;
    float bsum = bih[col] + bhh[col];
    #pragma unroll
    for (int i = 0; i < 4; ++i) {
      #pragma unroll
      for (int r = 0; r < 4; ++r) {
        int row = m0 + wm*64 + i*16 + quad*4 + r;
        int bb = row / 100;
        int tt = row - bb*100;
        xg[(tt*128 + bb)*512 + col] = acc[i][j][r] + bsum;
      }
    }
  }
}

// ---------------------------------------------------------------------------
// pv_lstm: unchanged from round 13.
// ---------------------------------------------------------------------------
__global__ __attribute__((amdgpu_waves_per_eu(4, 4)))
__launch_bounds__(1024) void pv_lstm(
    const float* xg, const float* Whh, float* hT)
{
  __shared__ __align__(16) unsigned short Hs[16*136];
  __shared__ float Ds[16*544];
  const int tid = threadIdx.x;
  const int wv = tid >> 6;
  const int lane = tid & 63;
  const int l16 = lane & 15, quad = lane >> 4;
  const int m0 = blockIdx.x * 16;

  s16x8 bfr[2][4];
  #pragma unroll
  for (int tt = 0; tt < 2; ++tt) {
    const int g = (wv*2 + tt)*16 + l16;
    #pragma unroll
    for (int c = 0; c < 4; ++c) {
      s16x8 v;
      #pragma unroll
      for (int e = 0; e < 8; ++e)
        v[e] = (short)pv_f2b(Whh[g*128 + c*32 + quad*8 + e]);
      bfr[tt][c] = v;
    }
  }
  for (int i = tid; i < 16*136; i += 1024) Hs[i] = 0;
  float cst[2] = {0.0f, 0.0f};
  __syncthreads();

  for (int t = 0; t < 100; ++t) {
    float xv[2][4];
    #pragma unroll
    for (int tt = 0; tt < 2; ++tt) {
      const int g = (wv*2 + tt)*16 + l16;
      #pragma unroll
      for (int r = 0; r < 4; ++r)
        xv[tt][r] = xg[(t*128 + m0 + quad*4 + r)*512 + g];
    }
    f32x4 acc0 = {0,0,0,0}, acc1 = {0,0,0,0};
    #pragma unroll
    for (int c = 0; c < 4; ++c) {
      s16x8 a = *(const s16x8*)(Hs + l16*136 + c*32 + quad*8);
      acc0 = __builtin_amdgcn_mfma_f32_16x16x32_bf16(a, bfr[0][c], acc0, 0, 0, 0);
      acc1 = __builtin_amdgcn_mfma_f32_16x16x32_bf16(a, bfr[1][c], acc1, 0, 0, 0);
    }
    #pragma unroll
    for (int r = 0; r < 4; ++r) {
      Ds[(quad*4 + r)*544 + (wv*2 + 0)*16 + l16] = acc0[r] + xv[0][r];
      Ds[(quad*4 + r)*544 + (wv*2 + 1)*16 + l16] = acc1[r] + xv[1][r];
    }
    __syncthreads();
    #pragma unroll
    for (int e = 0; e < 2; ++e) {
      const int el = tid + e*1024;
      const int m = el >> 7, j = el & 127;
      float gi = Ds[m*544 + j];
      float gf = Ds[m*544 + 128 + j];
      float gg = Ds[m*544 + 256 + j];
      float go = Ds[m*544 + 384 + j];
      float c = pv_sigm(gf)*cst[e] + pv_sigm(gi)*pv_tanh(gg);
      cst[e] = c;
      float h = pv_sigm(go)*pv_tanh(c);
      Hs[m*136 + j] = pv_f2b(h);
      if (t == 99) hT[(m0 + m)*128 + j] = h;
    }
    __syncthreads();
  }
}

// ---------------------------------------------------------------------------
// pv_head: unchanged.
// ---------------------------------------------------------------------------
__global__ __launch_bounds__(64) void pv_head(
    const float* hT, const float* eps,
    const float* muW, const float* mub,
    const float* lvW, const float* lvb,
    const float* fcW, const float* fcb,
    float* xvec, float* out)
{
  __shared__ float hrow[128];
  __shared__ float emb[64];
  const int b = blockIdx.x, j = threadIdx.x;
  hrow[j] = hT[b*128 + j];
  hrow[j + 64] = hT[b*128 + 64 + j];
  __syncthreads();
  float sm = mub[j], sl = lvb[j];
  for (int k = 0; k < 128; ++k) {
    sm += hrow[k]*muW[j*128 + k];
    sl += hrow[k]*lvW[j*128 + k];
  }
  float mu = fmaxf(sm, 0.1f*sm);
  float lv = fmaxf(sl, 0.1f*sl);
  lv = fminf(fmaxf(lv, -10.0f), 10.0f);
  float em = mu + eps[b*64 + j]*__expf(0.5f*lv);
  emb[j] = em;
  out[115200 + b*64 + j] = mu;
  out[123392 + b*64 + j] = lv;
  __syncthreads();
  for (int c4 = 0; c4 < 4; ++c4) {
    int c = c4*64 + j;
    float s = fcb[c];
    for (int k = 0; k < 64; ++k) s += emb[k]*fcW[c*64 + k];
    xvec[b*256 + c] = s;
  }
}

// ---------------------------------------------------------------------------
// pv_gxbase: unchanged.
// ---------------------------------------------------------------------------
__global__ __launch_bounds__(256) void pv_gxbase(
    const float* xvec, const float* Wih,
    const float* bih, const float* bhh, float* gxb)
{
  __shared__ float xs[8*256];
  const int tid = threadIdx.x;
  const int bg = blockIdx.x;
  const int gg = blockIdx.y;
  for (int i = tid; i < 2048; i += 256) xs[i] = xvec[bg*2048 + i];
  __syncthreads();
  const int g = gg*256 + tid;
  if (g >= 783) return;
  float bias = bih[g] + ((g < 522) ? bhh[g] : 0.0f);
  float a0=bias,a1=bias,a2=bias,a3=bias,a4=bias,a5=bias,a6=bias,a7=bias;
  const float* wr = Wih + g*261;
  for (int k = 0; k < 256; ++k) {
    float w = wr[k];
    a0 += xs[0*256 + k]*w; a1 += xs[1*256 + k]*w;
    a2 += xs[2*256 + k]*w; a3 += xs[3*256 + k]*w;
    a4 += xs[4*256 + k]*w; a5 += xs[5*256 + k]*w;
    a6 += xs[6*256 + k]*w; a7 += xs[7*256 + k]*w;
  }
  gxb[(bg*8 + 0)*783 + g] = a0; gxb[(bg*8 + 1)*783 + g] = a1;
  gxb[(bg*8 + 2)*783 + g] = a2; gxb[(bg*8 + 3)*783 + g] = a3;
  gxb[(bg*8 + 4)*783 + g] = a4; gxb[(bg*8 + 5)*783 + g] = a5;
  gxb[(bg*8 + 6)*783 + g] = a6; gxb[(bg*8 + 7)*783 + g] = a7;
}

// ---------------------------------------------------------------------------
// pv_gru: 32 WGs x 1024 threads, 4 batches/WG (rows 4..15 of the M-tile are
// zero pad).  fp8 MFMA for Whh·h (+ r/z noise/time via K-cols 261..265);
// update phase is ~1 elem/thread with ALL loop-invariants hoisted to regs:
// gxr/gxz/gxn, 0.1-scaled n-gate noise weights, bhh_n, pointers.  HW fp8
// encode.  Elements (m, 256..260) are a second elem for threads with j<5.
// ---------------------------------------------------------------------------
__global__ __attribute__((amdgpu_waves_per_eu(4, 4)))
__launch_bounds__(1024) void pv_gru(
    const float* gxb, const unsigned long long* wfp8, const float* Wih,
    const float* bhh, const float* noise, float* hseq)
{
  __shared__ __align__(16) unsigned char Afp8[16*296];  // A fp8, rows 4..15 = 0
  __shared__ float Ds[4*788];                           // D, row stride 788
  const int tid = threadIdx.x;
  const int wv = tid >> 6;
  const int lane = tid & 63;
  const int l16 = lane & 15, quad = lane >> 4;
  const int m0 = blockIdx.x * 4;
  const int tbase = (wv < 15) ? wv*3 : 45;
  const int ntiles = (wv < 15) ? 3 : 4;     // 49 tiles of 16 over 784 gates

  long bfr[4][9];
  #pragma unroll
  for (int tt = 0; tt < 4; ++tt) {
    if (tt < ntiles) {
      #pragma unroll
      for (int c = 0; c < 9; ++c)
        bfr[tt][c] = (long)wfp8[((tbase + tt)*9 + c)*64 + lane];
    } else {
      #pragma unroll
      for (int c = 0; c < 9; ++c) bfr[tt][c] = 0;
    }
  }

  // ---- hoisted per-thread update state: elem1 = (m_u, j_u) ----
  const int m_u = tid >> 8;          // 0..3
  const int j_u = tid & 255;         // 0..255
  const int sec = (j_u < 5);         // elem2 = (m_u, 256 + j_u)
  float wn0, wn1, wn2, wn3, wn4, bhhn, gxr, gxz, gxn;
  float wn0b=0, wn1b=0, wn2b=0, wn3b=0, wn4b=0, bhhnb=0, gxrb=0, gxzb=0, gxnb=0;
  {
    const float* wrow = Wih + (522 + j_u)*261 + 256;
    wn0 = 0.1f*wrow[0]; wn1 = 0.1f*wrow[1]; wn2 = 0.1f*wrow[2];
    wn3 = 0.1f*wrow[3]; wn4 = wrow[4];
    bhhn = bhh[522 + j_u];
    const float* gb = gxb + (m0 + m_u)*783;
    gxr = gb[j_u]; gxz = gb[261 + j_u]; gxn = gb[522 + j_u];
    if (sec) {
      const int j2 = 256 + j_u;
      const float* wrow2 = Wih + (522 + j2)*261 + 256;
      wn0b = 0.1f*wrow2[0]; wn1b = 0.1f*wrow2[1]; wn2b = 0.1f*wrow2[2];
      wn3b = 0.1f*wrow2[3]; wn4b = wrow2[4];
      bhhnb = bhh[522 + j2];
      gxrb = gb[j2]; gxzb = gb[261 + j2]; gxnb = gb[522 + j2];
    }
  }
  float* hptr = hseq + (m0 + m_u)*261 + j_u;
  const float* np = noise + (m0 + m_u)*4;
  float h1 = 0.0f, h2 = 0.0f;

  for (int i = tid; i < 16*296; i += 1024) Afp8[i] = 0;
  __syncthreads();
  if (tid < 20) {   // t=0 noise/time (time_0 = 0)
    const int m = tid/5, i = tid - (tid/5)*5;
    float v = (i < 4) ? noise[(m0 + m)*4 + i]*0.1f : 0.0f;
    Afp8[m*296 + 261 + i] = pv_fp8(4.0f*v);
  }
  __syncthreads();

  const float inv32 = 1.0f/32.0f;
  for (int t = 0; t < 100; ++t) {
    f32x4 acc[4];
    #pragma unroll
    for (int tt = 0; tt < 4; ++tt) acc[tt] = (f32x4){0,0,0,0};
    #pragma unroll
    for (int c = 0; c < 9; ++c) {
      const long a = *(const long*)(Afp8 + l16*296 + c*32 + quad*8);
      #pragma unroll
      for (int tt = 0; tt < 4; ++tt)
        if (tt < ntiles)
          acc[tt] = __builtin_amdgcn_mfma_f32_16x16x32_fp8_fp8(a, bfr[tt][c], acc[tt], 0, 0, 0);
    }
    if (quad == 0) {   // rows 0..3 are the real batches
      #pragma unroll
      for (int tt = 0; tt < 4; ++tt)
        if (tt < ntiles) {
          const int n = (tbase + tt)*16 + l16;
          #pragma unroll
          for (int r = 0; r < 4; ++r)
            Ds[r*788 + n] = acc[tt][r];
        }
    }
    __syncthreads();
    {
      const float tv = (float)t * (1.0f/99.0f);
      const float4 ne = *(const float4*)np;
      // elem1
      {
        const float* dm = Ds + m_u*788;
        float Dr = dm[j_u]*inv32 + gxr;
        float Dz = dm[261 + j_u]*inv32 + gxz;
        float Dn = dm[522 + j_u]*inv32;
        float nterm = ne.x*wn0 + ne.y*wn1 + ne.z*wn2 + ne.w*wn3 + tv*wn4;
        float r_ = pv_sigm(Dr);
        float z_ = pv_sigm(Dz);
        float n_ = pv_tanh(gxn + nterm + r_*(Dn + bhhn));
        h1 = (1.0f - z_)*n_ + z_*h1;
        hptr[0] = h1;
        Afp8[m_u*296 + j_u] = pv_fp8_fast(4.0f*h1);
      }
      // elem2 (j = 256 + j_u) for j_u < 5
      if (sec) {
        const int j2 = 256 + j_u;
        const float* dm = Ds + m_u*788;
        float Dr = dm[j2]*inv32 + gxrb;
        float Dz = dm[261 + j2]*inv32 + gxzb;
        float Dn = dm[522 + j2]*inv32;
        float nterm = ne.x*wn0b + ne.y*wn1b + ne.z*wn2b + ne.w*wn3b + tv*wn4b;
        float r_ = pv_sigm(Dr);
        float z_ = pv_sigm(Dz);
        float n_ = pv_tanh(gxnb + nterm + r_*(Dn + bhhnb));
        h2 = (1.0f - z_)*n_ + z_*h2;
        hptr[256] = h2;
        Afp8[m_u*296 + j2] = pv_fp8_fast(4.0f*h2);
      }
    }
    if (tid < 20 && t < 99) {   // noise/time for t+1
      const int m = tid/5, i = tid - (tid/5)*5;
      float v = (i < 4) ? noise[((t+1)*128 + m0 + m)*4 + i]*0.1f
                        : (t+1)*(1.0f/99.0f);
      Afp8[m*296 + 261 + i] = pv_fp8(4.0f*v);
    }
    hptr += 128*261;
    np += 512;
    __syncthreads();
  }
}

// ---------------------------------------------------------------------------
// pv_frames: unchanged.
// ---------------------------------------------------------------------------
__global__ __launch_bounds__(256) void pv_frames(
    const float* hseq, const float* W1, const float* b1,
    const float* W2, const float* b2, float* out)
{
  __shared__ __align__(16) float h16[16*264];
  __shared__ unsigned w1p[64*133];
  __shared__ float f1s[16*66];
  __shared__ float w2s[576];
  const int tid = threadIdx.x;
  const int r0 = blockIdx.x * 16;    // rows rt = t*128 + b
  for (int i = tid; i < 16*264; i += 256) {
    int r = i / 264, k = i - r*264;
    h16[i] = (k < 261) ? hseq[(r0 + r)*261 + k] : 0.0f;
  }
  for (int i = tid; i < 64*131; i += 256) {
    int c = i/131, kp = i - (i/131)*131;
    int k = kp*2;
    float a0 = W1[c*261 + k];
    float a1 = (k + 1 < 261) ? W1[c*261 + k + 1] : 0.0f;
    w1p[c*133 + kp] = pv_pack2(a0, a1);
  }
  for (int i = tid; i < 576; i += 256) w2s[i] = W2[i];
  __syncthreads();
  #pragma unroll
  for (int e = 0; e < 4; ++e) {
    const int el = tid + e*256;
    const int r = el >> 6, c = el & 63;
    float s = b1[c];
    const unsigned* wp = w1p + c*133;
    const float* hr = h16 + r*264;
    for (int kp = 0; kp < 131; ++kp) {
      unsigned w = wp[kp];
      s += pv_lo(w)*hr[2*kp] + pv_hi(w)*hr[2*kp + 1];
    }
    f1s[r*66 + c] = fmaxf(s, 0.2f*s);
  }
  __syncthreads();
  if (tid < 144) {
    const int r = tid/9, oc = tid - (tid/9)*9;
    float s = b2[oc];
    const float* fr = f1s + r*66;
    const float* w = w2s + oc*64;
    #pragma unroll 8
    for (int k = 0; k < 64; ++k) s += fr[k]*w[k];
    const int rt = r0 + r;
    const int tt = rt >> 7, bb = rt & 127;
    out[bb*900 + tt*9 + oc] = pv_sigm(s);
  }
}

// ---------------------------------------------------------------------------
extern "C" __attribute__((visibility("default")))
void kernel_launch(void* const* d_in, const int* in_sizes, int n_in,
                   void* d_out, int out_size, void* d_ws, size_t ws_size,
                   hipStream_t stream)
{
  (void)in_sizes; (void)n_in; (void)out_size; (void)ws_size;
  const float* input_data = (const float*)d_in[0];
  const float* eps        = (const float*)d_in[1];
  const float* noise_eps  = (const float*)d_in[2];
  const float* proj_W     = (const float*)d_in[3];
  const float* proj_b     = (const float*)d_in[4];
  const float* lstm_Wih   = (const float*)d_in[5];
  const float* lstm_Whh   = (const float*)d_in[6];
  const float* lstm_bih   = (const float*)d_in[7];
  const float* lstm_bhh   = (const float*)d_in[8];
  const float* mu_W       = (const float*)d_in[9];
  const float* mu_b       = (const float*)d_in[10];
  const float* lv_W       = (const float*)d_in[11];
  const float* lv_b       = (const float*)d_in[12];
  const float* fcin_W     = (const float*)d_in[13];
  const float* fcin_b     = (const float*)d_in[14];
  const float* gru_Wih    = (const float*)d_in[15];
  const float* gru_Whh    = (const float*)d_in[16];
  const float* gru_bih    = (const float*)d_in[17];
  const float* gru_bhh    = (const float*)d_in[18];
  const float* jf_W1      = (const float*)d_in[19];
  const float* jf_b1      = (const float*)d_in[20];
  const float* jf_W2      = (const float*)d_in[21];
  const float* jf_b2      = (const float*)d_in[22];

  char* w = (char*)d_ws;
  float*              xg   = (float*)(w);                          // 26,214,400 B
  unsigned long long* wfp8 = (unsigned long long*)(w + 26214400);  //    225,792 B
  float*              hT   = (float*)(w + 26440192);               //     65,536 B
  float*              xvec = (float*)(w + 26505728);               //    131,072 B
  float*              gxb  = (float*)(w + 26636800);               //    400,896 B
  float*              hseq = (float*)(w + 27037696);               // 13,363,200 B (end 40.4 MB)
  float*              outf = (float*)d_out;

  pv_prep_gru8<<<111, 256, 0, stream>>>(gru_Whh, gru_Wih, wfp8);
  pv_gemm<<<dim3(100, 4), 256, 0, stream>>>(input_data, proj_W, proj_b,
                                            lstm_Wih, lstm_bih, lstm_bhh, xg);
  pv_lstm<<<8, 1024, 0, stream>>>(xg, lstm_Whh, hT);
  pv_head<<<128, 64, 0, stream>>>(hT, eps, mu_W, mu_b, lv_W, lv_b,
                                  fcin_W, fcin_b, xvec, outf);
  pv_gxbase<<<dim3(16, 4), 256, 0, stream>>>(xvec, gru_Wih, gru_bih, gru_bhh, gxb);
  pv_gru<<<32, 1024, 0, stream>>>(gxb, wfp8, gru_Wih, gru_bhh, noise_eps, hseq);
  pv_frames<<<800, 256, 0, stream>>>(hseq, jf_W1, jf_b1, jf_W2, jf_b2, outf);
}